// Round 1
// baseline (399.632 us; speedup 1.0000x reference)
//
#include <hip/hip_runtime.h>
#include <math.h>

// 14-qubit, 6-layer RX+CNOT-ring circuit simulator, batch 512.
//
// Design:
//  - One workgroup per batch element; full 16384-amplitude complex state in
//    LDS as float2 (128 KB). 512 threads (8 waves), 1 block/CU (LDS-bound).
//  - CNOT ring absorbed into a GF(2) linear relabeling of index bits:
//      C[q] = column q of L  (XOR mask pairing RX on logical qubit q)
//      R[q] = row q of L^-1  (logical bit q of slot l = parity(l & R[q]))
//    absorbing CNOT(c->t):  C[c] ^= C[t];  R[t] ^= R[c];   (no data motion)
//  - Init state closed form: state[i] = (-i)^popc(i) * prod_q (bit? sin : cos).
//  - Output: <Z_q> = sum_l |amp_l|^2 * (1 - 2*parity(l & R[q])) with final R.

#define NQ 14
#define DIM 16384
#define NLAYERS 6
#define BATCH 512
#define THREADS 512
#define NWAVES (THREADS / 64)
#define AMPS_PER_THREAD (DIM / THREADS)      // 32
#define PAIRS_PER_THREAD (DIM / 2 / THREADS) // 16

__global__ __launch_bounds__(THREADS, 1)
void qsim_kernel(const float* __restrict__ x,
                 const float* __restrict__ params,
                 float* __restrict__ out)
{
    __shared__ float2 sv[DIM];            // 131072 B state (re, im)
    __shared__ float cx[NQ], sx[NQ];      // cos/sin of x/2 per qubit
    __shared__ float gc[NQ], gs[NQ];      // cos/sin of theta/2 per gate, this layer
    __shared__ unsigned int sC[NQ];       // columns of L
    __shared__ unsigned int sR[NQ];       // rows of L^-1
    __shared__ float lowtab[32];          // product over qubits 9..13 per 5-bit pattern
    __shared__ float red[NWAVES][NQ];     // cross-wave reduction buffer

    const int b   = blockIdx.x;
    const int tid = threadIdx.x;

    // --- per-batch init angles + identity relabeling ---
    if (tid < NQ) {
        float h = 0.5f * x[b * NQ + tid];
        cx[tid] = cosf(h);
        sx[tid] = sinf(h);
        sC[tid] = 1u << (NQ - 1 - tid);   // qubit q <-> bit position 13-q
        sR[tid] = 1u << (NQ - 1 - tid);
    }
    __syncthreads();

    // low 5 bit positions p=0..4 <-> qubits 13..9
    if (tid < 32) {
        float m = 1.0f;
        #pragma unroll
        for (int p = 0; p < 5; ++p) {
            int q = NQ - 1 - p;
            m *= ((tid >> p) & 1) ? sx[q] : cx[q];
        }
        lowtab[tid] = m;
    }
    // high product: bit positions 5..13 <-> qubits 8..0; l = tid*32 + j
    float hiprod = 1.0f;
    #pragma unroll
    for (int p = 5; p < NQ; ++p) {
        int q = NQ - 1 - p;
        hiprod *= ((tid >> (p - 5)) & 1) ? sx[q] : cx[q];
    }
    __syncthreads();

    // --- initialize state: amp = (-i)^popc(l) * hiprod * lowtab ---
    for (int j = 0; j < AMPS_PER_THREAD; ++j) {
        unsigned int l = (unsigned)tid * AMPS_PER_THREAD + j;
        float m = hiprod * lowtab[l & 31u];
        int k = __popc(l) & 3;
        float2 v;
        v.x = (k == 0) ? m : ((k == 2) ? -m : 0.0f);
        v.y = (k == 1) ? -m : ((k == 3) ? m : 0.0f);
        sv[l] = v;
    }
    __syncthreads();

    // --- main circuit ---
    for (int layer = 0; layer < NLAYERS; ++layer) {
        if (tid < NQ) {
            float h = 0.5f * params[layer * NQ + tid];
            gc[tid] = cosf(h);
            gs[tid] = sinf(h);
        }
        __syncthreads();

        for (int q = 0; q < NQ; ++q) {
            const unsigned int m = sC[q];
            const unsigned int r = sR[q];
            const float c = gc[q];
            const float s = gs[q];
            const int piv = __ffs(m) - 1;             // a set bit of m: pairing pivot
            const unsigned int lowmask = (1u << piv) - 1u;

            for (int it = 0; it < PAIRS_PER_THREAD; ++it) {
                unsigned int p  = (unsigned)tid + (unsigned)it * THREADS;
                unsigned int l  = ((p & ~lowmask) << 1) | (p & lowmask); // bit piv == 0
                unsigned int l2 = l ^ m;                                  // bit piv == 1
                // role: logical bit q at slot l
                unsigned int par = __popc(l & r) & 1u;
                unsigned int i0 = par ? l2 : l;   // holds logical-bit-q = 0
                unsigned int i1 = i0 ^ m;         // holds logical-bit-q = 1
                float2 a0 = sv[i0];
                float2 a1 = sv[i1];
                // RX: n0 = c*a0 - i s*a1 ; n1 = -i s*a0 + c*a1
                float2 n0, n1;
                n0.x = c * a0.x + s * a1.y;
                n0.y = c * a0.y - s * a1.x;
                n1.x = s * a0.y + c * a1.x;
                n1.y = c * a1.y - s * a0.x;
                sv[i0] = n0;
                sv[i1] = n1;
            }
            __syncthreads();
        }

        // absorb this layer's CNOT ring into the relabeling (thread 0)
        if (tid == 0) {
            #pragma unroll
            for (int g = 0; g < NQ; ++g) {
                int cq = g;
                int tq = (g + 1) % NQ;
                sC[cq] ^= sC[tq];
                sR[tq] ^= sR[cq];
            }
        }
        __syncthreads();
    }

    // --- expectation values <Z_q> ---
    float acc[NQ];
    #pragma unroll
    for (int q = 0; q < NQ; ++q) acc[q] = 0.0f;
    unsigned int rm[NQ];
    #pragma unroll
    for (int q = 0; q < NQ; ++q) rm[q] = sR[q];

    for (int j = 0; j < AMPS_PER_THREAD; ++j) {
        unsigned int l = (unsigned)tid * AMPS_PER_THREAD + j;
        float2 v = sv[l];
        float pr = v.x * v.x + v.y * v.y;
        #pragma unroll
        for (int q = 0; q < NQ; ++q) {
            acc[q] += (__popc(l & rm[q]) & 1u) ? -pr : pr;
        }
    }

    // wave-level reduce (width 64), then cross-wave via LDS
    #pragma unroll
    for (int q = 0; q < NQ; ++q) {
        #pragma unroll
        for (int off = 32; off > 0; off >>= 1)
            acc[q] += __shfl_down(acc[q], off, 64);
    }
    const int wave = tid >> 6;
    const int lane = tid & 63;
    if (lane == 0) {
        #pragma unroll
        for (int q = 0; q < NQ; ++q) red[wave][q] = acc[q];
    }
    __syncthreads();
    if (tid < NQ) {
        float sum = 0.0f;
        #pragma unroll
        for (int w = 0; w < NWAVES; ++w) sum += red[w][tid];
        out[b * NQ + tid] = sum;
    }
}

extern "C" void kernel_launch(void* const* d_in, const int* in_sizes, int n_in,
                              void* d_out, int out_size, void* d_ws, size_t ws_size,
                              hipStream_t stream) {
    const float* x      = (const float*)d_in[0];   // (512, 14) float32
    const float* params = (const float*)d_in[1];   // (6, 1, 14) float32
    float* out          = (float*)d_out;           // (512, 14) float32
    qsim_kernel<<<BATCH, THREADS, 0, stream>>>(x, params, out);
}

// Round 2
// 225.204 us; speedup vs baseline: 1.7745x; 1.7745x over previous
//
#include <hip/hip_runtime.h>
#include <math.h>

// 14-qubit, 6-layer RX+CNOT-ring circuit simulator, batch 512.
//
// R2: 5-way gate fusion. Each LDS pass loads a 2^K-amplitude subcube
// (spanned by the K group masks C[q]) into registers, applies K RX
// butterflies in-register, writes back. RX is symmetric (c*I - i*s*X),
// so the logical-bit role of each slot is irrelevant in the gate loop —
// R (rows of L^-1) is only needed for the final Z-expectation signs.
// Passes/layer: 14 -> 3 (5+5+4); total LDS passes 84 -> 18.
//
// Coset enumeration: reduced Gaussian elimination on the K masks with
// pivots chosen as HIGHEST set bits, so the (14-K)-bit coset counter maps
// to the low non-pivot bits -> consecutive lanes read consecutive float2
// addresses -> conflict-free ds_read_b64 in most passes.

#define NQ 14
#define DIM 16384
#define NLAYERS 6
#define BATCH 512
#define THREADS 512
#define NWAVES (THREADS / 64)
#define AMPS_PER_THREAD (DIM / THREADS)      // 32

template<int K>
__device__ __forceinline__ void rx_pass(float2* __restrict__ sv,
                                        const unsigned int* __restrict__ sC,
                                        const float* __restrict__ gc,
                                        const float* __restrict__ gs,
                                        int q0, int tid)
{
    constexpr int NAMP = 1 << K;             // amps per coset
    constexpr int NCOSET = DIM >> K;
    constexpr int PER_THREAD = NCOSET / THREADS; // 1 (K=5) or 2 (K=4)

    unsigned int m[K];
    float c[K], s[K];
    #pragma unroll
    for (int i = 0; i < K; ++i) {
        m[i] = __builtin_amdgcn_readfirstlane(sC[q0 + i]); // uniform -> SGPR
        c[i] = gc[q0 + i];
        s[i] = gs[q0 + i];
    }

    // reduced echelon form of the K masks; pivots = highest set bits.
    unsigned int e[K];
    #pragma unroll
    for (int i = 0; i < K; ++i) e[i] = m[i];
    unsigned int pivmask = 0;
    #pragma unroll
    for (int i = 0; i < K; ++i) {
        int p = 31 - __clz(e[i]);            // masks are lin. indep -> e[i]!=0
        pivmask |= 1u << p;
        #pragma unroll
        for (int j = 0; j < K; ++j)
            if (j != i && ((e[j] >> p) & 1u)) e[j] ^= e[i];
    }

    // off[j] = XOR of m[i] for set bits i of j (register-resident, uniform)
    unsigned int off[NAMP];
    off[0] = 0;
    #pragma unroll
    for (int j = 1; j < NAMP; ++j)
        off[j] = off[j & (j - 1)] ^ m[__builtin_ctz(j)];

    #pragma unroll
    for (int it = 0; it < PER_THREAD; ++it) {
        unsigned int t = (unsigned int)tid + (unsigned int)(it * THREADS);
        // scatter counter t into the non-pivot bit positions (low-to-low)
        unsigned int base = 0;
        int src = 0;
        for (int p = 0; p < NQ; ++p) {
            if (!((pivmask >> p) & 1u)) {
                base |= ((t >> src) & 1u) << p;
                ++src;
            }
        }

        float2 v[NAMP];
        #pragma unroll
        for (int j = 0; j < NAMP; ++j) v[j] = sv[base ^ off[j]];

        #pragma unroll
        for (int i = 0; i < K; ++i) {
            const float ci = c[i], si = s[i];
            #pragma unroll
            for (int j = 0; j < NAMP; ++j) {
                if (j & (1 << i)) continue;
                const int j1 = j | (1 << i);
                const float2 a0 = v[j], a1 = v[j1];
                // RX: n0 = c*a0 - i*s*a1 ; n1 = -i*s*a0 + c*a1 (symmetric)
                v[j].x  = ci * a0.x + si * a1.y;
                v[j].y  = ci * a0.y - si * a1.x;
                v[j1].x = si * a0.y + ci * a1.x;
                v[j1].y = ci * a1.y - si * a0.x;
            }
        }

        #pragma unroll
        for (int j = 0; j < NAMP; ++j) sv[base ^ off[j]] = v[j];
    }
}

__global__ __launch_bounds__(THREADS, 1)
void qsim_kernel(const float* __restrict__ x,
                 const float* __restrict__ params,
                 float* __restrict__ out)
{
    __shared__ float2 sv[DIM];            // 131072 B state (re, im)
    __shared__ float cx[NQ], sx[NQ];      // cos/sin of x/2 per qubit
    __shared__ float gc[NQ], gs[NQ];      // cos/sin of theta/2, current layer
    __shared__ unsigned int sC[NQ];       // columns of L
    __shared__ unsigned int sR[NQ];       // rows of L^-1
    __shared__ float lowtab[32];
    __shared__ float red[NWAVES][NQ];

    const int b   = blockIdx.x;
    const int tid = threadIdx.x;

    // --- per-batch init angles + identity relabeling + layer-0 gate angles ---
    if (tid < NQ) {
        float h = 0.5f * x[b * NQ + tid];
        cx[tid] = cosf(h);
        sx[tid] = sinf(h);
        sC[tid] = 1u << (NQ - 1 - tid);
        sR[tid] = 1u << (NQ - 1 - tid);
    }
    if (tid >= 64 && tid < 64 + NQ) {
        int q = tid - 64;
        float h = 0.5f * params[q];
        gc[q] = cosf(h);
        gs[q] = sinf(h);
    }
    __syncthreads();

    // low 5 bit positions p=0..4 <-> qubits 13..9
    if (tid < 32) {
        float m = 1.0f;
        #pragma unroll
        for (int p = 0; p < 5; ++p) {
            int q = NQ - 1 - p;
            m *= ((tid >> p) & 1) ? sx[q] : cx[q];
        }
        lowtab[tid] = m;
    }
    float hiprod = 1.0f;
    #pragma unroll
    for (int p = 5; p < NQ; ++p) {
        int q = NQ - 1 - p;
        hiprod *= ((tid >> (p - 5)) & 1) ? sx[q] : cx[q];
    }
    __syncthreads();

    // --- initialize state: amp = (-i)^popc(l) * hiprod * lowtab ---
    for (int j = 0; j < AMPS_PER_THREAD; ++j) {
        unsigned int l = (unsigned int)tid * AMPS_PER_THREAD + j;
        float m = hiprod * lowtab[l & 31u];
        int k = __popc(l) & 3;
        float2 v;
        v.x = (k == 0) ? m : ((k == 2) ? -m : 0.0f);
        v.y = (k == 1) ? -m : ((k == 3) ? m : 0.0f);
        sv[l] = v;
    }
    __syncthreads();

    // --- main circuit: 3 fused passes per layer ---
    for (int layer = 0; layer < NLAYERS; ++layer) {
        rx_pass<5>(sv, sC, gc, gs, 0, tid);
        __syncthreads();
        rx_pass<5>(sv, sC, gc, gs, 5, tid);
        __syncthreads();
        rx_pass<4>(sv, sC, gc, gs, 10, tid);
        __syncthreads();

        // absorb CNOT ring (wave 0, thread 0) + load next layer's angles (wave 1)
        if (tid == 0) {
            #pragma unroll
            for (int g = 0; g < NQ; ++g) {
                int cq = g;
                int tq = (g + 1) % NQ;
                sC[cq] ^= sC[tq];
                sR[tq] ^= sR[cq];
            }
        }
        if (layer + 1 < NLAYERS && tid >= 64 && tid < 64 + NQ) {
            int q = tid - 64;
            float h = 0.5f * params[(layer + 1) * NQ + q];
            gc[q] = cosf(h);
            gs[q] = sinf(h);
        }
        __syncthreads();
    }

    // --- expectation values <Z_q> with final R ---
    float acc[NQ];
    #pragma unroll
    for (int q = 0; q < NQ; ++q) acc[q] = 0.0f;
    unsigned int rm[NQ];
    #pragma unroll
    for (int q = 0; q < NQ; ++q) rm[q] = __builtin_amdgcn_readfirstlane(sR[q]);

    for (int j = 0; j < AMPS_PER_THREAD; ++j) {
        unsigned int l = (unsigned int)tid * AMPS_PER_THREAD + j;
        float2 v = sv[l];
        float pr = v.x * v.x + v.y * v.y;
        #pragma unroll
        for (int q = 0; q < NQ; ++q) {
            acc[q] += (__popc(l & rm[q]) & 1u) ? -pr : pr;
        }
    }

    #pragma unroll
    for (int q = 0; q < NQ; ++q) {
        #pragma unroll
        for (int off = 32; off > 0; off >>= 1)
            acc[q] += __shfl_down(acc[q], off, 64);
    }
    const int wave = tid >> 6;
    const int lane = tid & 63;
    if (lane == 0) {
        #pragma unroll
        for (int q = 0; q < NQ; ++q) red[wave][q] = acc[q];
    }
    __syncthreads();
    if (tid < NQ) {
        float sum = 0.0f;
        #pragma unroll
        for (int w = 0; w < NWAVES; ++w) sum += red[w][tid];
        out[b * NQ + tid] = sum;
    }
}

extern "C" void kernel_launch(void* const* d_in, const int* in_sizes, int n_in,
                              void* d_out, int out_size, void* d_ws, size_t ws_size,
                              hipStream_t stream) {
    const float* x      = (const float*)d_in[0];   // (512, 14) float32
    const float* params = (const float*)d_in[1];   // (6, 1, 14) float32
    float* out          = (float*)d_out;           // (512, 14) float32
    qsim_kernel<<<BATCH, THREADS, 0, stream>>>(x, params, out);
}

// Round 3
// 150.816 us; speedup vs baseline: 2.6498x; 1.4932x over previous
//
#include <hip/hip_runtime.h>
#include <math.h>

// 14-qubit, 6-layer RX+CNOT-ring circuit, batch 512 — closed-form Walsh method.
//
// Every CNOT-absorbed gate is c*I - i*s*P_m (P_m = XOR-by-m permutation).
// All P_m commute; H^{x14} diagonalizes them all: H P_m H = diag((-1)^<k,m>).
// The RX product initial state maps under H to pure phases:
//   chi_k = 2^-7 * exp(i W_k),  W_k = 1/2 sum_q (bit_{13-q}(k) ? +x_q : -x_q)
// The diagonal circuit multiplies by E_k = exp(-i Theta_k),
//   Theta_k = 1/2 sum_g eps_g(k) theta_g,  eps_g(k) = (-1)^{popc(k & m_g)}
// (batch-independent!). With F_k = chi~_k * E_k (unit phases), pushing the
// Z_q observables through the final Hadamard gives XOR-lag autocorrelations:
//   out[b][q] = 2^-14 * sum_k Re[ conj(F_k) * F_{k ^ r_q} ]
// where r_q = final readout masks (rows of the accumulated CNOT map),
// identical to the sR recurrence of the previous (passing) kernel.

#define NQ 14
#define DIM 16384
#define NLAYERS 6
#define BATCH 512
#define T2 1024                 // threads, kernel 2
#define JPT (DIM / T2)          // 16 k-values per thread

struct Tabs {
    unsigned short m[NLAYERS][NQ];  // gate masks per layer (pre-update sC)
    unsigned short r[NQ];           // final readout lag masks (sR after 6 layers)
};

constexpr Tabs gen_tabs() {
    Tabs T{};
    unsigned short C[NQ] = {}, R[NQ] = {};
    for (int q = 0; q < NQ; ++q) { C[q] = (unsigned short)(1u << (NQ - 1 - q)); R[q] = C[q]; }
    for (int l = 0; l < NLAYERS; ++l) {
        for (int q = 0; q < NQ; ++q) T.m[l][q] = C[q];
        for (int g = 0; g < NQ; ++g) {          // sequential, matches passing R2 kernel
            int t = (g + 1) % NQ;
            C[g] = (unsigned short)(C[g] ^ C[t]);
            R[t] = (unsigned short)(R[t] ^ R[g]);
        }
    }
    for (int q = 0; q < NQ; ++q) T.r[q] = R[q];
    return T;
}
constexpr Tabs TAB = gen_tabs();

// ---------------- kernel 1: batch-independent phase table E ----------------
__global__ __launch_bounds__(512)
void build_E(const float* __restrict__ params, float2* __restrict__ E)
{
    __shared__ float th[NLAYERS * NQ];
    const int tid = threadIdx.x;
    if (tid < NLAYERS * NQ) th[tid] = params[tid];
    __syncthreads();

    const int k = blockIdx.x * 512 + tid;
    double acc = 0.0;                       // Theta_k, fp64 for phase accuracy
    #pragma unroll
    for (int l = 0; l < NLAYERS; ++l) {
        #pragma unroll
        for (int q = 0; q < NQ; ++q) {
            const int par = __popc(k & (int)TAB.m[l][q]) & 1;
            const float t = th[l * NQ + q];
            acc += par ? -(double)(0.5f * t) : (double)(0.5f * t);
        }
    }
    float s, c;
    __sincosf(0.0f, &s, &c);                // keep fast path resident (no-op)
    sincosf((float)acc, &s, &c);            // accurate large-arg reduction
    E[k] = make_float2(c, -s);              // e^{-i Theta}
}

// ---------------- kernel 2: per-batch correlations ----------------
__global__ __launch_bounds__(T2, 1)
void qcorr(const float* __restrict__ x,
           const float2* __restrict__ E,
           float* __restrict__ out)
{
    __shared__ float2 F[DIM];               // 131072 B phase table
    __shared__ float sx[NQ];
    __shared__ float2 hi[JPT];              // e^{i Whigh(j)}
    __shared__ float red[T2 / 64][NQ];

    const int b = blockIdx.x;
    const int t = threadIdx.x;

    if (t < NQ) sx[t] = x[b * NQ + t];
    __syncthreads();

    // hi table: index bit positions 10..13 <-> qubits 3..0
    if (t < JPT) {
        float w = 0.0f;
        #pragma unroll
        for (int p = 10; p < 14; ++p) {
            const float xv = sx[13 - p];
            w += ((t >> (p - 10)) & 1) ? 0.5f * xv : -0.5f * xv;
        }
        float s, c; sincosf(w, &s, &c);
        hi[t] = make_float2(c, s);
    }

    // Wlow: index bit positions 0..9 <-> qubits 13..4 (bits of t)
    float w = 0.0f;
    #pragma unroll
    for (int p = 0; p < 10; ++p) {
        const float xv = sx[13 - p];
        w += ((t >> p) & 1) ? 0.5f * xv : -0.5f * xv;
    }
    float s0, c0; sincosf(w, &s0, &c0);     // e^{i Wlow}

    __syncthreads();                        // hi ready

    // F_k = e^{iW} * E_k ; keep own 16 in registers, stage all in LDS
    float2 Freg[JPT];
    #pragma unroll
    for (int j = 0; j < JPT; ++j) {
        const int k = t + (j << 10);
        const float2 e = E[k];              // coalesced, LLC-resident
        const float2 h = hi[j];
        const float ux = c0 * h.x - s0 * h.y;
        const float uy = c0 * h.y + s0 * h.x;
        float2 f;
        f.x = ux * e.x - uy * e.y;
        f.y = ux * e.y + uy * e.x;
        Freg[j] = f;
        F[k] = f;                           // consecutive lanes -> conflict-free
    }
    __syncthreads();

    // out_q = 2^-14 sum_k Re[conj(F_k) F_{k^r_q}]
    float acc[NQ];
    #pragma unroll
    for (int q = 0; q < NQ; ++q) acc[q] = 0.0f;

    #pragma unroll
    for (int q = 0; q < NQ; ++q) {
        const int r    = (int)TAB.r[q];
        const int txor = t ^ (r & (T2 - 1));
        const int rhi  = r >> 10;
        #pragma unroll
        for (int j = 0; j < JPT; ++j) {
            // lanes read an XOR-permuted contiguous 64-block -> conflict-free
            const float2 g = F[txor + ((j ^ rhi) << 10)];
            acc[q] += Freg[j].x * g.x + Freg[j].y * g.y;
        }
    }

    // reduce across 1024 threads
    #pragma unroll
    for (int q = 0; q < NQ; ++q) {
        #pragma unroll
        for (int off = 32; off > 0; off >>= 1)
            acc[q] += __shfl_down(acc[q], off, 64);
    }
    const int wave = t >> 6;
    const int lane = t & 63;
    if (lane == 0) {
        #pragma unroll
        for (int q = 0; q < NQ; ++q) red[wave][q] = acc[q];
    }
    __syncthreads();
    if (t < NQ) {
        float sum = 0.0f;
        #pragma unroll
        for (int wv = 0; wv < T2 / 64; ++wv) sum += red[wv][t];
        out[b * NQ + t] = sum * (1.0f / (float)DIM);
    }
}

extern "C" void kernel_launch(void* const* d_in, const int* in_sizes, int n_in,
                              void* d_out, int out_size, void* d_ws, size_t ws_size,
                              hipStream_t stream) {
    const float* x      = (const float*)d_in[0];   // (512, 14) float32
    const float* params = (const float*)d_in[1];   // (6, 1, 14) float32
    float* out          = (float*)d_out;           // (512, 14) float32
    float2* E           = (float2*)d_ws;           // 16384 * 8 B = 128 KB scratch

    build_E<<<DIM / 512, 512, 0, stream>>>(params, E);
    qcorr<<<BATCH, T2, 0, stream>>>(x, E, out);
}